// Round 9
// baseline (313.498 us; speedup 1.0000x reference)
//
#include <hip/hip_runtime.h>
#include <hip/hip_bf16.h>

#define D_MODEL 1024
#define D_HEAD  64
#define T_SEQ   4096
#define NB      4
#define NROWS   (NB * T_SEQ)      // 16384
#define SPLIT   8

typedef float f32x4 __attribute__((ext_vector_type(4)));
typedef __bf16 bf16x8 __attribute__((ext_vector_type(8)));
typedef unsigned short u16;

__device__ inline unsigned pk_bf16(float a, float b) {
    unsigned ua = __builtin_bit_cast(unsigned, a);
    unsigned ub = __builtin_bit_cast(unsigned, b);
    ua = (ua + 0x7FFFu + ((ua >> 16) & 1u)) >> 16;   // RNE
    ub = (ub + 0x7FFFu + ((ub >> 16) & 1u)) >> 16;
    return ua | (ub << 16);
}
__device__ inline u16 bf16r(float a) {
    unsigned ua = __builtin_bit_cast(unsigned, a);
    return (u16)((ua + 0x7FFFu + ((ua >> 16) & 1u)) >> 16);
}

// ---------------- W pre-pack: Wpk[kb][n][j] = W_sel[(kb*8+j)*64 + col], bf16 ----------------
__global__ __launch_bounds__(256) void packw_kernel(
    const float* __restrict__ Wq, const float* __restrict__ Wk,
    const float* __restrict__ Wv, unsigned* __restrict__ Wpk)
{
    const int id = blockIdx.x * 256 + threadIdx.x;   // 0..24575
    const int kb = id / 192;
    const int n  = id - kb * 192;
    const int sel = n >> 6, col = n & 63;
    const float* W = sel == 0 ? Wq : (sel == 1 ? Wk : Wv);
    float f[8];
#pragma unroll
    for (int j = 0; j < 8; ++j) f[j] = W[(kb * 8 + j) * 64 + col];
    uint4 o;
    o.x = pk_bf16(f[0], f[1]); o.y = pk_bf16(f[2], f[3]);
    o.z = pk_bf16(f[4], f[5]); o.w = pk_bf16(f[6], f[7]);
    *(uint4*)(Wpk + (size_t)id * 4) = o;
}

// ---------------- QKV projection: rolled loop + explicit depth-1 register prefetch ----------
// 3072 blocks x 64 thr (3 waves/SIMD). Block: m-tile = bid/3 (16 rows), c = bid%3 (Q,K,V).
// NOT fully unrolled (R6-R8 full unroll -> compiler either spilled or serialized);
// instead a rolled loop with next-iteration x/W fragments loaded into explicit temps.
__global__ __launch_bounds__(64, 4) void qkv_kernel(
    const float* __restrict__ x, const unsigned* __restrict__ Wpk,
    u16* __restrict__ Qbf, u16* __restrict__ Kbf, u16* __restrict__ Vt)
{
    __shared__ __align__(16) u16 Vbuf[64 * 16];      // c==2 epilogue transpose tile

    const int bid  = blockIdx.x;
    const int m    = bid / 3;
    const int c    = bid - m * 3;            // 0:Q 1:K 2:V
    const long row0 = (long)m * 16;
    const int lane = threadIdx.x;
    const int nl   = lane & 15;
    const int quad = lane >> 4;

    const float* xp = x + (row0 + nl) * D_MODEL + quad * 8;
    const unsigned* wb0 = Wpk + (size_t)quad * 768 + (c * 64 + nl) * 4;

    f32x4 acc[4] = {};

    float4 a0 = *(const float4*)(xp);
    float4 a1 = *(const float4*)(xp + 4);
    uint4 bfr[4];
#pragma unroll
    for (int t = 0; t < 4; ++t) bfr[t] = *(const uint4*)(wb0 + t * 64);

#pragma unroll 2
    for (int k0 = 0; k0 < D_MODEL; k0 += 32) {
        float4 na0, na1;
        uint4 nb[4];
        if (k0 + 32 < D_MODEL) {             // prefetch next step's fragments
            na0 = *(const float4*)(xp + k0 + 32);
            na1 = *(const float4*)(xp + k0 + 36);
            const unsigned* wbn = wb0 + (size_t)((k0 + 32) >> 3) * 768;
#pragma unroll
            for (int t = 0; t < 4; ++t) nb[t] = *(const uint4*)(wbn + t * 64);
        }
        uint4 ap;
        ap.x = pk_bf16(a0.x, a0.y); ap.y = pk_bf16(a0.z, a0.w);
        ap.z = pk_bf16(a1.x, a1.y); ap.w = pk_bf16(a1.z, a1.w);
        const bf16x8 a = __builtin_bit_cast(bf16x8, ap);
#pragma unroll
        for (int t = 0; t < 4; ++t)
            acc[t] = __builtin_amdgcn_mfma_f32_16x16x32_bf16(
                a, __builtin_bit_cast(bf16x8, bfr[t]), acc[t], 0, 0, 0);
        a0 = na0; a1 = na1;
#pragma unroll
        for (int t = 0; t < 4; ++t) bfr[t] = nb[t];
    }

    // epilogue: C/D row=quad*4+reg, col=t*16+nl
    if (c == 0) {
        const float QSCALE = 0.04508422f;    // D^-0.5 * log2(e): exp2-domain prescale
#pragma unroll
        for (int t = 0; t < 4; ++t)
#pragma unroll
            for (int reg = 0; reg < 4; ++reg)
                Qbf[(row0 + quad * 4 + reg) * D_HEAD + t * 16 + nl] = bf16r(acc[t][reg] * QSCALE);
    } else if (c == 1) {
#pragma unroll
        for (int t = 0; t < 4; ++t)
#pragma unroll
            for (int reg = 0; reg < 4; ++reg)
                Kbf[(row0 + quad * 4 + reg) * D_HEAD + t * 16 + nl] = bf16r(acc[t][reg]);
    } else {
        // V^T via LDS bounce: C-layout -> Vbuf[h][16 t] -> coalesced 32B row stores
#pragma unroll
        for (int t = 0; t < 4; ++t) {
            uint2 pk2;
            pk2.x = pk_bf16(acc[t][0], acc[t][1]);
            pk2.y = pk_bf16(acc[t][2], acc[t][3]);
            *(uint2*)&Vbuf[(t * 16 + nl) * 16 + quad * 4] = pk2;
        }
        __syncthreads();                     // single wave: just drains LDS
        const long bb   = row0 >> 12;        // 16-row tiles never straddle batch
        const int tpos0 = (int)(row0 & 4095);
        const uint4 va = *(const uint4*)&Vbuf[lane * 16];
        const uint4 vb = *(const uint4*)&Vbuf[lane * 16 + 8];
        u16* dst = &Vt[((bb * 64 + lane) << 12) + tpos0];
        *(uint4*)dst       = va;
        *(uint4*)(dst + 8) = vb;
    }
}

// ---------------- MFMA flash attention: barrier-free, K-split x8, bf16 partials ----------------
// 2048 blocks x 256 thr (= 4 waves); global split sp = half*4 + wave. 8 blocks/CU ->
// ~8 waves/SIMD so HW multithreading hides the per-tile load->MFMA->exp2->LDS chain.
// Shift-free softmax (m=0 exact: |logit| < ~1). Partial O stored bf16 in [col][row16]
// layout (C-layout reg-pairs pack contiguously -> uint2 stores).
__global__ __launch_bounds__(256, 8) void attn_kernel(
    const u16* __restrict__ Qbf, const u16* __restrict__ Kbf,
    const u16* __restrict__ Vt, u16* __restrict__ Po16, float* __restrict__ Pl)
{
    __shared__ __align__(16) u16 Pbuf[4][16 * 64];

    const int tid   = threadIdx.x;
    const int w     = tid >> 6;
    const int lane  = tid & 63;
    const int nl    = lane & 15;
    const int quad  = lane >> 4;
    const int b     = blockIdx.x & 3;
    const int idx   = blockIdx.x >> 2;           // 0..511
    const int strip = 255 - (idx >> 1);          // long strips launch first
    const int sp    = (idx & 1) * 4 + w;         // global split 0..7
    const int wq0   = strip * 16;

    const u16* Kb = Kbf + (size_t)b * T_SEQ * D_HEAD;
    const u16* Vb = Vt  + (size_t)b * D_HEAD * T_SEQ;

    // Q A-frags: A[m=nl][k=quad*8+j], rows wq0+nl
    const u16* qp = Qbf + ((size_t)b * T_SEQ + wq0 + nl) * D_HEAD + quad * 8;
    const bf16x8 qf0 = __builtin_bit_cast(bf16x8, *(const uint4*)qp);
    const bf16x8 qf1 = __builtin_bit_cast(bf16x8, *(const uint4*)(qp + 32));

    f32x4 Ot[4] = {};
    float l[4] = {0.f, 0.f, 0.f, 0.f};
    const int nt = (wq0 + 79) >> 6;              // ceil((wq0+16)/64)
    u16* pb = Pbuf[w];

    for (int kt = sp; kt < nt; kt += SPLIT) {
        const int k0 = kt << 6;

        // K B-frags direct from global (contiguous row bytes)
        uint4 kfr[4][2];
#pragma unroll
        for (int t = 0; t < 4; ++t) {
            const u16* kp = Kb + (size_t)(k0 + t * 16 + nl) * D_HEAD + quad * 8;
            kfr[t][0] = *(const uint4*)kp;
            kfr[t][1] = *(const uint4*)(kp + 32);
        }
        // V B-frags direct from global Vt rows — issued now, consumed after softmax
        uint4 vfr[4][2];
#pragma unroll
        for (int t = 0; t < 4; ++t) {
            const u16* vp = Vb + (size_t)(t * 16 + nl) * T_SEQ + k0 + quad * 8;
            vfr[t][0] = *(const uint4*)vp;
            vfr[t][1] = *(const uint4*)(vp + 32);
        }

        // S = Q K^T
        f32x4 S[4];
#pragma unroll
        for (int t = 0; t < 4; ++t) {
            f32x4 z = {};
            z = __builtin_amdgcn_mfma_f32_16x16x32_bf16(qf0,
                    __builtin_bit_cast(bf16x8, kfr[t][0]), z, 0, 0, 0);
            S[t] = __builtin_amdgcn_mfma_f32_16x16x32_bf16(qf1,
                    __builtin_bit_cast(bf16x8, kfr[t][1]), z, 0, 0, 0);
        }

        // causal mask (fires only on the diagonal tile)
        if (k0 + 63 > wq0) {
#pragma unroll
            for (int t = 0; t < 4; ++t)
#pragma unroll
                for (int reg = 0; reg < 4; ++reg)
                    if (k0 + t * 16 + nl > wq0 + quad * 4 + reg) S[t][reg] = -INFINITY;
        }

        // shift-free softmax: p = exp2(S), per-lane partial row sums
#pragma unroll
        for (int t = 0; t < 4; ++t)
#pragma unroll
            for (int reg = 0; reg < 4; ++reg)
                S[t][reg] = exp2f(S[t][reg]);
#pragma unroll
        for (int reg = 0; reg < 4; ++reg)
            l[reg] += (S[0][reg] + S[1][reg]) + (S[2][reg] + S[3][reg]);

        // P: C-layout -> per-wave LDS -> A-layout (wave-coherent, no barrier)
#pragma unroll
        for (int t = 0; t < 4; ++t) {
            const int g = 2 * t + (nl >> 3);
#pragma unroll
            for (int reg = 0; reg < 4; ++reg) {
                const int q = quad * 4 + reg;
                pb[q * 64 + ((g ^ (q & 7)) * 8) + (nl & 7)] = bf16r(S[t][reg]);
            }
        }
        const bf16x8 pf0 = __builtin_bit_cast(bf16x8,
            *(const uint4*)&pb[nl * 64 + ((quad ^ (nl & 7)) * 8)]);
        const bf16x8 pf1 = __builtin_bit_cast(bf16x8,
            *(const uint4*)&pb[nl * 64 + (((4 + quad) ^ (nl & 7)) * 8)]);

        // O += P V
#pragma unroll
        for (int t = 0; t < 4; ++t) {
            Ot[t] = __builtin_amdgcn_mfma_f32_16x16x32_bf16(pf0,
                        __builtin_bit_cast(bf16x8, vfr[t][0]), Ot[t], 0, 0, 0);
            Ot[t] = __builtin_amdgcn_mfma_f32_16x16x32_bf16(pf1,
                        __builtin_bit_cast(bf16x8, vfr[t][1]), Ot[t], 0, 0, 0);
        }
    }

    // reduce l across the 16 col-lanes
#pragma unroll
    for (int reg = 0; reg < 4; ++reg) {
        float s = l[reg];
        s += __shfl_xor(s, 1);
        s += __shfl_xor(s, 2);
        s += __shfl_xor(s, 4);
        s += __shfl_xor(s, 8);
        l[reg] = s;
    }
    // partial O in bf16, layout Po16[sp][bs][col 64][row 16]; reg-pairs are contiguous
    const int bs = b * 256 + strip;
    u16* po = Po16 + ((size_t)sp * 1024 + bs) * 1024;
#pragma unroll
    for (int t = 0; t < 4; ++t) {
        uint2 p2;
        p2.x = pk_bf16(Ot[t][0], Ot[t][1]);
        p2.y = pk_bf16(Ot[t][2], Ot[t][3]);
        *(uint2*)&po[(t * 16 + nl) * 16 + quad * 4] = p2;
    }
    if (nl == 0) {
        const size_t gr = (size_t)b * T_SEQ + wq0;
#pragma unroll
        for (int reg = 0; reg < 4; ++reg)
            Pl[(size_t)sp * NROWS + gr + quad * 4 + reg] = l[reg];
    }
}

// ---------------- merge K-split partials: O[row][col] = sum_sp Po / sum_sp Pl ----------------
// 1024 blocks (one per b,strip) x 64 thr (thread = col). Po cols are contiguous 16-row
// vectors; out writes are col-coalesced.
__global__ __launch_bounds__(64) void reduce_kernel(
    const u16* __restrict__ Po16, const float* __restrict__ Pl,
    float* __restrict__ O)
{
    __shared__ float linv[16];
    const int bs    = blockIdx.x;
    const int b     = bs >> 8, strip = bs & 255;
    const size_t gr = (size_t)b * T_SEQ + strip * 16;
    const int c     = threadIdx.x;               // col 0..63

    if (c < 16) {
        float s = 0.f;
#pragma unroll
        for (int sp = 0; sp < SPLIT; ++sp) s += Pl[(size_t)sp * NROWS + gr + c];
        linv[c] = 1.0f / s;
    }
    __syncthreads();

    float v[16] = {};
#pragma unroll
    for (int sp = 0; sp < SPLIT; ++sp) {
        const u16* p = Po16 + ((size_t)sp * 1024 + bs) * 1024 + c * 16;
        const uint4 x0 = *(const uint4*)p;
        const uint4 x1 = *(const uint4*)(p + 8);
        const unsigned uu[8] = {x0.x, x0.y, x0.z, x0.w, x1.x, x1.y, x1.z, x1.w};
#pragma unroll
        for (int i = 0; i < 8; ++i) {
            v[2*i]   += __builtin_bit_cast(float, uu[i] << 16);
            v[2*i+1] += __builtin_bit_cast(float, uu[i] & 0xFFFF0000u);
        }
    }
#pragma unroll
    for (int r = 0; r < 16; ++r)
        O[(gr + r) * D_HEAD + c] = v[r] * linv[r];
}

extern "C" void kernel_launch(void* const* d_in, const int* in_sizes, int n_in,
                              void* d_out, int out_size, void* d_ws, size_t ws_size,
                              hipStream_t stream) {
    const float* x  = (const float*)d_in[0];
    const float* Wq = (const float*)d_in[1];
    const float* Wk = (const float*)d_in[2];
    const float* Wv = (const float*)d_in[3];
    float* out = (float*)d_out;

    const size_t rows = NROWS;                        // 16384
    u16* Qbf = (u16*)d_ws;                            // 2 MB
    u16* Kbf = Qbf + rows * D_HEAD;                   // 2 MB
    u16* Vt  = Kbf + rows * D_HEAD;                   // 2 MB (per-batch transposed [b][h][t])
    unsigned* Wpk = (unsigned*)(Vt + rows * D_HEAD);  // 384 KB
    u16* Po16 = (u16*)(Wpk + 128 * 192 * 4);          // SPLIT*16384*64 bf16 = 16 MB
    float* Pl = (float*)(Po16 + (size_t)SPLIT * rows * D_HEAD);  // 512 KB

    hipLaunchKernelGGL(packw_kernel, dim3(96), dim3(256), 0, stream,
                       Wq, Wk, Wv, Wpk);
    hipLaunchKernelGGL(qkv_kernel, dim3(3 * rows / 16), dim3(64), 0, stream,
                       x, Wpk, Qbf, Kbf, Vt);
    hipLaunchKernelGGL(attn_kernel, dim3(NB * 512), dim3(256), 0, stream,
                       Qbf, Kbf, Vt, Po16, Pl);
    hipLaunchKernelGGL(reduce_kernel, dim3(NB * 256), dim3(64), 0, stream,
                       Po16, Pl, out);
}

// Round 10
// 205.855 us; speedup vs baseline: 1.5229x; 1.5229x over previous
//
#include <hip/hip_runtime.h>
#include <hip/hip_bf16.h>

#define D_MODEL 1024
#define D_HEAD  64
#define T_SEQ   4096
#define NB      4
#define NROWS   (NB * T_SEQ)      // 16384
#define SPLIT   8

typedef float f32x4 __attribute__((ext_vector_type(4)));
typedef __bf16 bf16x8 __attribute__((ext_vector_type(8)));
typedef unsigned short u16;

__device__ inline unsigned pk_bf16(float a, float b) {
    unsigned ua = __builtin_bit_cast(unsigned, a);
    unsigned ub = __builtin_bit_cast(unsigned, b);
    ua = (ua + 0x7FFFu + ((ua >> 16) & 1u)) >> 16;   // RNE
    ub = (ub + 0x7FFFu + ((ub >> 16) & 1u)) >> 16;
    return ua | (ub << 16);
}
__device__ inline u16 bf16r(float a) {
    unsigned ua = __builtin_bit_cast(unsigned, a);
    return (u16)((ua + 0x7FFFu + ((ua >> 16) & 1u)) >> 16);
}

// ---------------- W pre-pack: Wpk[kb][n][j] = W_sel[(kb*8+j)*64 + col], bf16 ----------------
__global__ __launch_bounds__(256) void packw_kernel(
    const float* __restrict__ Wq, const float* __restrict__ Wk,
    const float* __restrict__ Wv, unsigned* __restrict__ Wpk)
{
    const int id = blockIdx.x * 256 + threadIdx.x;   // 0..24575
    const int kb = id / 192;
    const int n  = id - kb * 192;
    const int sel = n >> 6, col = n & 63;
    const float* W = sel == 0 ? Wq : (sel == 1 ? Wk : Wv);
    float f[8];
#pragma unroll
    for (int j = 0; j < 8; ++j) f[j] = W[(kb * 8 + j) * 64 + col];
    uint4 o;
    o.x = pk_bf16(f[0], f[1]); o.y = pk_bf16(f[2], f[3]);
    o.z = pk_bf16(f[4], f[5]); o.w = pk_bf16(f[6], f[7]);
    *(uint4*)(Wpk + (size_t)id * 4) = o;
}

// ---------------- QKV projection: 3 waves/block (wave = Q|K|V chunk), shared x rows ----------
// 1024 blocks x 192 thr. All 3 waves read IDENTICAL x addresses for the same 16 rows ->
// x global traffic /3 (served from L1/L2 broadcast). Rolled loop + depth-1 reg prefetch.
// No barriers: the only LDS (Vbuf) is private to wave 2 (intra-wave ordering via lgkmcnt).
__global__ __launch_bounds__(192, 4) void qkv_kernel(
    const float* __restrict__ x, const unsigned* __restrict__ Wpk,
    u16* __restrict__ Qbf, u16* __restrict__ Kbf, u16* __restrict__ Vt)
{
    __shared__ __align__(16) u16 Vbuf[64 * 16];      // used only by wave c==2

    const int c    = threadIdx.x >> 6;       // 0:Q 1:K 2:V
    const long row0 = (long)blockIdx.x * 16;
    const int lane = threadIdx.x & 63;
    const int nl   = lane & 15;
    const int quad = lane >> 4;

    const float* xp = x + (row0 + nl) * D_MODEL + quad * 8;
    const unsigned* wb0 = Wpk + (size_t)quad * 768 + (c * 64 + nl) * 4;

    f32x4 acc[4] = {};

    float4 a0 = *(const float4*)(xp);
    float4 a1 = *(const float4*)(xp + 4);
    uint4 bfr[4];
#pragma unroll
    for (int t = 0; t < 4; ++t) bfr[t] = *(const uint4*)(wb0 + t * 64);

#pragma unroll 2
    for (int k0 = 0; k0 < D_MODEL; k0 += 32) {
        float4 na0, na1;
        uint4 nb[4];
        if (k0 + 32 < D_MODEL) {             // prefetch next step's fragments
            na0 = *(const float4*)(xp + k0 + 32);
            na1 = *(const float4*)(xp + k0 + 36);
            const unsigned* wbn = wb0 + (size_t)((k0 + 32) >> 3) * 768;
#pragma unroll
            for (int t = 0; t < 4; ++t) nb[t] = *(const uint4*)(wbn + t * 64);
        }
        uint4 ap;
        ap.x = pk_bf16(a0.x, a0.y); ap.y = pk_bf16(a0.z, a0.w);
        ap.z = pk_bf16(a1.x, a1.y); ap.w = pk_bf16(a1.z, a1.w);
        const bf16x8 a = __builtin_bit_cast(bf16x8, ap);
#pragma unroll
        for (int t = 0; t < 4; ++t)
            acc[t] = __builtin_amdgcn_mfma_f32_16x16x32_bf16(
                a, __builtin_bit_cast(bf16x8, bfr[t]), acc[t], 0, 0, 0);
        a0 = na0; a1 = na1;
#pragma unroll
        for (int t = 0; t < 4; ++t) bfr[t] = nb[t];
    }

    // epilogue: C/D row=quad*4+reg, col=t*16+nl
    if (c == 0) {
        const float QSCALE = 0.04508422f;    // D^-0.5 * log2(e): exp2-domain prescale
#pragma unroll
        for (int t = 0; t < 4; ++t)
#pragma unroll
            for (int reg = 0; reg < 4; ++reg)
                Qbf[(row0 + quad * 4 + reg) * D_HEAD + t * 16 + nl] = bf16r(acc[t][reg] * QSCALE);
    } else if (c == 1) {
#pragma unroll
        for (int t = 0; t < 4; ++t)
#pragma unroll
            for (int reg = 0; reg < 4; ++reg)
                Kbf[(row0 + quad * 4 + reg) * D_HEAD + t * 16 + nl] = bf16r(acc[t][reg]);
    } else {
        // V^T via wave-private LDS bounce: C-layout -> Vbuf[col][row16] -> 32B row stores
#pragma unroll
        for (int t = 0; t < 4; ++t) {
            uint2 pk2;
            pk2.x = pk_bf16(acc[t][0], acc[t][1]);
            pk2.y = pk_bf16(acc[t][2], acc[t][3]);
            *(uint2*)&Vbuf[(t * 16 + nl) * 16 + quad * 4] = pk2;
        }
        // intra-wave LDS write->read: compiler inserts lgkmcnt wait; no barrier needed
        const long bb   = row0 >> 12;        // 16-row tiles never straddle batch
        const int tpos0 = (int)(row0 & 4095);
        const uint4 va = *(const uint4*)&Vbuf[lane * 16];
        const uint4 vb = *(const uint4*)&Vbuf[lane * 16 + 8];
        u16* dst = &Vt[((bb * 64 + lane) << 12) + tpos0];
        *(uint4*)dst       = va;
        *(uint4*)(dst + 8) = vb;
    }
}

// ---------------- MFMA flash attention: EXACT R8 kernel (79 us known-good) ----------------
// Barrier-free, K-split x8, 4 waves/block, (256,4) -> VGPR 64 (NOT 8: R9's (256,8)
// forced VGPR 32 -> 600 MB scratch-spill traffic, 2.2x slower).
__global__ __launch_bounds__(256, 4) void attn_kernel(
    const u16* __restrict__ Qbf, const u16* __restrict__ Kbf,
    const u16* __restrict__ Vt, u16* __restrict__ Po16, float* __restrict__ Pl)
{
    __shared__ __align__(16) u16 Pbuf[4][16 * 64];

    const int tid   = threadIdx.x;
    const int w     = tid >> 6;
    const int lane  = tid & 63;
    const int nl    = lane & 15;
    const int quad  = lane >> 4;
    const int b     = blockIdx.x & 3;
    const int idx   = blockIdx.x >> 2;           // 0..511
    const int strip = 255 - (idx >> 1);          // long strips launch first
    const int sp    = (idx & 1) * 4 + w;         // global split 0..7
    const int wq0   = strip * 16;

    const u16* Kb = Kbf + (size_t)b * T_SEQ * D_HEAD;
    const u16* Vb = Vt  + (size_t)b * D_HEAD * T_SEQ;

    // Q A-frags: A[m=nl][k=quad*8+j], rows wq0+nl
    const u16* qp = Qbf + ((size_t)b * T_SEQ + wq0 + nl) * D_HEAD + quad * 8;
    const bf16x8 qf0 = __builtin_bit_cast(bf16x8, *(const uint4*)qp);
    const bf16x8 qf1 = __builtin_bit_cast(bf16x8, *(const uint4*)(qp + 32));

    f32x4 Ot[4] = {};
    float l[4] = {0.f, 0.f, 0.f, 0.f};
    const int nt = (wq0 + 79) >> 6;              // ceil((wq0+16)/64)
    u16* pb = Pbuf[w];

    for (int kt = sp; kt < nt; kt += SPLIT) {
        const int k0 = kt << 6;

        // K B-frags direct from global (contiguous row bytes)
        uint4 kfr[4][2];
#pragma unroll
        for (int t = 0; t < 4; ++t) {
            const u16* kp = Kb + (size_t)(k0 + t * 16 + nl) * D_HEAD + quad * 8;
            kfr[t][0] = *(const uint4*)kp;
            kfr[t][1] = *(const uint4*)(kp + 32);
        }
        // V B-frags direct from global Vt rows — issued now, consumed after softmax
        uint4 vfr[4][2];
#pragma unroll
        for (int t = 0; t < 4; ++t) {
            const u16* vp = Vb + (size_t)(t * 16 + nl) * T_SEQ + k0 + quad * 8;
            vfr[t][0] = *(const uint4*)vp;
            vfr[t][1] = *(const uint4*)(vp + 32);
        }

        // S = Q K^T
        f32x4 S[4];
#pragma unroll
        for (int t = 0; t < 4; ++t) {
            f32x4 z = {};
            z = __builtin_amdgcn_mfma_f32_16x16x32_bf16(qf0,
                    __builtin_bit_cast(bf16x8, kfr[t][0]), z, 0, 0, 0);
            S[t] = __builtin_amdgcn_mfma_f32_16x16x32_bf16(qf1,
                    __builtin_bit_cast(bf16x8, kfr[t][1]), z, 0, 0, 0);
        }

        // causal mask (fires only on the diagonal tile)
        if (k0 + 63 > wq0) {
#pragma unroll
            for (int t = 0; t < 4; ++t)
#pragma unroll
                for (int reg = 0; reg < 4; ++reg)
                    if (k0 + t * 16 + nl > wq0 + quad * 4 + reg) S[t][reg] = -INFINITY;
        }

        // shift-free softmax: p = exp2(S), per-lane partial row sums
#pragma unroll
        for (int t = 0; t < 4; ++t)
#pragma unroll
            for (int reg = 0; reg < 4; ++reg)
                S[t][reg] = exp2f(S[t][reg]);
#pragma unroll
        for (int reg = 0; reg < 4; ++reg)
            l[reg] += (S[0][reg] + S[1][reg]) + (S[2][reg] + S[3][reg]);

        // P: C-layout -> per-wave LDS -> A-layout (wave-coherent, no barrier)
#pragma unroll
        for (int t = 0; t < 4; ++t) {
            const int g = 2 * t + (nl >> 3);
#pragma unroll
            for (int reg = 0; reg < 4; ++reg) {
                const int q = quad * 4 + reg;
                pb[q * 64 + ((g ^ (q & 7)) * 8) + (nl & 7)] = bf16r(S[t][reg]);
            }
        }
        const bf16x8 pf0 = __builtin_bit_cast(bf16x8,
            *(const uint4*)&pb[nl * 64 + ((quad ^ (nl & 7)) * 8)]);
        const bf16x8 pf1 = __builtin_bit_cast(bf16x8,
            *(const uint4*)&pb[nl * 64 + (((4 + quad) ^ (nl & 7)) * 8)]);

        // O += P V
#pragma unroll
        for (int t = 0; t < 4; ++t) {
            Ot[t] = __builtin_amdgcn_mfma_f32_16x16x32_bf16(pf0,
                        __builtin_bit_cast(bf16x8, vfr[t][0]), Ot[t], 0, 0, 0);
            Ot[t] = __builtin_amdgcn_mfma_f32_16x16x32_bf16(pf1,
                        __builtin_bit_cast(bf16x8, vfr[t][1]), Ot[t], 0, 0, 0);
        }
    }

    // reduce l across the 16 col-lanes
#pragma unroll
    for (int reg = 0; reg < 4; ++reg) {
        float s = l[reg];
        s += __shfl_xor(s, 1);
        s += __shfl_xor(s, 2);
        s += __shfl_xor(s, 4);
        s += __shfl_xor(s, 8);
        l[reg] = s;
    }
    // partial O in bf16, layout Po16[sp][bs][col 64][row 16]; reg-pairs are contiguous
    const int bs = b * 256 + strip;
    u16* po = Po16 + ((size_t)sp * 1024 + bs) * 1024;
#pragma unroll
    for (int t = 0; t < 4; ++t) {
        uint2 p2;
        p2.x = pk_bf16(Ot[t][0], Ot[t][1]);
        p2.y = pk_bf16(Ot[t][2], Ot[t][3]);
        *(uint2*)&po[(t * 16 + nl) * 16 + quad * 4] = p2;
    }
    if (nl == 0) {
        const size_t gr = (size_t)b * T_SEQ + wq0;
#pragma unroll
        for (int reg = 0; reg < 4; ++reg)
            Pl[(size_t)sp * NROWS + gr + quad * 4 + reg] = l[reg];
    }
}

// ---------------- merge K-split partials: O[row][col] = sum_sp Po / sum_sp Pl ----------------
__global__ __launch_bounds__(64) void reduce_kernel(
    const u16* __restrict__ Po16, const float* __restrict__ Pl,
    float* __restrict__ O)
{
    __shared__ float linv[16];
    const int bs    = blockIdx.x;
    const int b     = bs >> 8, strip = bs & 255;
    const size_t gr = (size_t)b * T_SEQ + strip * 16;
    const int c     = threadIdx.x;               // col 0..63

    if (c < 16) {
        float s = 0.f;
#pragma unroll
        for (int sp = 0; sp < SPLIT; ++sp) s += Pl[(size_t)sp * NROWS + gr + c];
        linv[c] = 1.0f / s;
    }
    __syncthreads();

    float v[16] = {};
#pragma unroll
    for (int sp = 0; sp < SPLIT; ++sp) {
        const u16* p = Po16 + ((size_t)sp * 1024 + bs) * 1024 + c * 16;
        const uint4 x0 = *(const uint4*)p;
        const uint4 x1 = *(const uint4*)(p + 8);
        const unsigned uu[8] = {x0.x, x0.y, x0.z, x0.w, x1.x, x1.y, x1.z, x1.w};
#pragma unroll
        for (int i = 0; i < 8; ++i) {
            v[2*i]   += __builtin_bit_cast(float, uu[i] << 16);
            v[2*i+1] += __builtin_bit_cast(float, uu[i] & 0xFFFF0000u);
        }
    }
#pragma unroll
    for (int r = 0; r < 16; ++r)
        O[(gr + r) * D_HEAD + c] = v[r] * linv[r];
}

extern "C" void kernel_launch(void* const* d_in, const int* in_sizes, int n_in,
                              void* d_out, int out_size, void* d_ws, size_t ws_size,
                              hipStream_t stream) {
    const float* x  = (const float*)d_in[0];
    const float* Wq = (const float*)d_in[1];
    const float* Wk = (const float*)d_in[2];
    const float* Wv = (const float*)d_in[3];
    float* out = (float*)d_out;

    const size_t rows = NROWS;                        // 16384
    u16* Qbf = (u16*)d_ws;                            // 2 MB
    u16* Kbf = Qbf + rows * D_HEAD;                   // 2 MB
    u16* Vt  = Kbf + rows * D_HEAD;                   // 2 MB (per-batch transposed [b][h][t])
    unsigned* Wpk = (unsigned*)(Vt + rows * D_HEAD);  // 384 KB
    u16* Po16 = (u16*)(Wpk + 128 * 192 * 4);          // SPLIT*16384*64 bf16 = 16 MB
    float* Pl = (float*)(Po16 + (size_t)SPLIT * rows * D_HEAD);  // 512 KB

    hipLaunchKernelGGL(packw_kernel, dim3(96), dim3(256), 0, stream,
                       Wq, Wk, Wv, Wpk);
    hipLaunchKernelGGL(qkv_kernel, dim3(rows / 16), dim3(192), 0, stream,
                       x, Wpk, Qbf, Kbf, Vt);
    hipLaunchKernelGGL(attn_kernel, dim3(NB * 512), dim3(256), 0, stream,
                       Qbf, Kbf, Vt, Po16, Pl);
    hipLaunchKernelGGL(reduce_kernel, dim3(NB * 256), dim3(64), 0, stream,
                       Po16, Pl, out);
}

// Round 11
// 199.501 us; speedup vs baseline: 1.5714x; 1.0318x over previous
//
#include <hip/hip_runtime.h>
#include <hip/hip_bf16.h>

#define D_MODEL 1024
#define D_HEAD  64
#define T_SEQ   4096
#define NB      4
#define NROWS   (NB * T_SEQ)      // 16384
#define NITEMS  2112              // attn work items per batch (variable split)

typedef float f32x4 __attribute__((ext_vector_type(4)));
typedef __bf16 bf16x8 __attribute__((ext_vector_type(8)));
typedef unsigned short u16;

__device__ inline unsigned pk_bf16(float a, float b) {
    unsigned ua = __builtin_bit_cast(unsigned, a);
    unsigned ub = __builtin_bit_cast(unsigned, b);
    ua = (ua + 0x7FFFu + ((ua >> 16) & 1u)) >> 16;   // RNE
    ub = (ub + 0x7FFFu + ((ub >> 16) & 1u)) >> 16;
    return ua | (ub << 16);
}
__device__ inline u16 bf16r(float a) {
    unsigned ua = __builtin_bit_cast(unsigned, a);
    return (u16)((ua + 0x7FFFu + ((ua >> 16) & 1u)) >> 16);
}

// ---------------- W pre-pack: Wpk[kb][n][j] = W_sel[(kb*8+j)*64 + col], bf16 ----------------
__global__ __launch_bounds__(256) void packw_kernel(
    const float* __restrict__ Wq, const float* __restrict__ Wk,
    const float* __restrict__ Wv, unsigned* __restrict__ Wpk)
{
    const int id = blockIdx.x * 256 + threadIdx.x;   // 0..24575
    const int kb = id / 192;
    const int n  = id - kb * 192;
    const int sel = n >> 6, col = n & 63;
    const float* W = sel == 0 ? Wq : (sel == 1 ? Wk : Wv);
    float f[8];
#pragma unroll
    for (int j = 0; j < 8; ++j) f[j] = W[(kb * 8 + j) * 64 + col];
    uint4 o;
    o.x = pk_bf16(f[0], f[1]); o.y = pk_bf16(f[2], f[3]);
    o.z = pk_bf16(f[4], f[5]); o.w = pk_bf16(f[6], f[7]);
    *(uint4*)(Wpk + (size_t)id * 4) = o;
}

// ---------------- QKV projection: streaming LDS-staged GEMM, BK=128 dbuf ----------------
// 512 blocks x 256 thr (4 waves). Tile 32 rows x 192 cols; wave w owns cols [w*48,+48).
// x staged fp32->bf16 via PERFECTLY COALESCED loads (512B/row contiguous, 2 rows/wave-instr),
// depth-1 chunk prefetch in regs (16KB/block in flight). LDS stride 136 bf16 (+8 pad).
__global__ __launch_bounds__(256) void qkv_kernel(
    const float* __restrict__ x, const unsigned* __restrict__ Wpk,
    u16* __restrict__ Qbf, u16* __restrict__ Kbf, u16* __restrict__ Vt)
{
    __shared__ __align__(16) unsigned Xs[2][32 * 68];   // 32 rows x 128 bf16 (stride 136)
    __shared__ __align__(16) u16 Vbuf[64 * 32];         // V^T bounce: [dim 64][tpos 32]

    const int tid  = threadIdx.x;
    const int w    = tid >> 6;
    const int lane = tid & 63;
    const int nl   = lane & 15;
    const int quad = lane >> 4;
    const long row0 = (long)blockIdx.x * 32;

    const int srow = tid >> 5;          // staging: base row 0..7 (+8 per pass)
    const int scol = (tid & 31) * 4;    // staging col 0..124

    f32x4 acc[2][3] = {};

    float4 nx[4];
#pragma unroll
    for (int p = 0; p < 4; ++p)
        nx[p] = *(const float4*)(x + (row0 + p * 8 + srow) * D_MODEL + scol);

    for (int ch = 0; ch < 8; ++ch) {
        const int buf = ch & 1;
        // pack prefetched chunk into LDS
#pragma unroll
        for (int p = 0; p < 4; ++p) {
            uint2 pk2;
            pk2.x = pk_bf16(nx[p].x, nx[p].y);
            pk2.y = pk_bf16(nx[p].z, nx[p].w);
            *(uint2*)&Xs[buf][(p * 8 + srow) * 68 + (scol >> 1)] = pk2;
        }
        __syncthreads();
        if (ch < 7) {                    // prefetch next chunk while computing
#pragma unroll
            for (int p = 0; p < 4; ++p)
                nx[p] = *(const float4*)(x + (row0 + p * 8 + srow) * D_MODEL
                                           + (ch + 1) * 128 + scol);
        }
#pragma unroll
        for (int kk = 0; kk < 4; ++kk) {
            const bf16x8 a0 = __builtin_bit_cast(bf16x8,
                *(const uint4*)&Xs[buf][nl * 68 + kk * 16 + quad * 4]);
            const bf16x8 a1 = __builtin_bit_cast(bf16x8,
                *(const uint4*)&Xs[buf][(16 + nl) * 68 + kk * 16 + quad * 4]);
            const unsigned* wb = Wpk + (size_t)(ch * 16 + kk * 4 + quad) * 768
                                     + (w * 48 + nl) * 4;
#pragma unroll
            for (int t = 0; t < 3; ++t) {
                const bf16x8 b = __builtin_bit_cast(bf16x8, *(const uint4*)(wb + t * 64));
                acc[0][t] = __builtin_amdgcn_mfma_f32_16x16x32_bf16(a0, b, acc[0][t], 0, 0, 0);
                acc[1][t] = __builtin_amdgcn_mfma_f32_16x16x32_bf16(a1, b, acc[1][t], 0, 0, 0);
            }
        }
        __syncthreads();                 // LDS reads done before next overwrite cycle
    }

    // epilogue: C/D row=quad*4+reg, col=(w*48+t*16)&63 + nl
    const float QSCALE = 0.04508422f;    // D^-0.5 * log2(e): exp2-domain prescale
#pragma unroll
    for (int t = 0; t < 3; ++t) {
        const int n0c = w * 48 + t * 16;
        const int sel = n0c >> 6;
        const int col = (n0c & 63) + nl;
#pragma unroll
        for (int m = 0; m < 2; ++m) {
            if (sel == 0) {
#pragma unroll
                for (int reg = 0; reg < 4; ++reg)
                    Qbf[(row0 + m * 16 + quad * 4 + reg) * D_HEAD + col] =
                        bf16r(acc[m][t][reg] * QSCALE);
            } else if (sel == 1) {
#pragma unroll
                for (int reg = 0; reg < 4; ++reg)
                    Kbf[(row0 + m * 16 + quad * 4 + reg) * D_HEAD + col] =
                        bf16r(acc[m][t][reg]);
            } else {
                // V: stage into Vbuf[dim][tpos] (reg-pairs contiguous in tpos)
                uint2 p2;
                p2.x = pk_bf16(acc[m][t][0], acc[m][t][1]);
                p2.y = pk_bf16(acc[m][t][2], acc[m][t][3]);
                *(uint2*)&Vbuf[col * 32 + m * 16 + quad * 4] = p2;
            }
        }
    }
    __syncthreads();
    // Vt writeout: thread i covers dim=i>>2, 8 t-positions
    {
        const int dim  = tid >> 2;
        const int tseg = (tid & 3) * 8;
        const long bb   = row0 >> 12;        // 32-row tiles never straddle batch
        const int tpos0 = (int)(row0 & 4095);
        const uint4 v = *(const uint4*)&Vbuf[dim * 32 + tseg];
        *(uint4*)&Vt[((bb * 64 + dim) << 12) + tpos0 + tseg] = v;
    }
}

// ---------------- MFMA flash attention: barrier-free inner loop, VARIABLE K-split ----------
// Work item g in [0,2112) per batch: strips 192-255 split 16x, 96-191 8x, 32-95 4x,
// 0-31 2x -> max ~6 tiles/wave (was 8), 2112 blocks with backfill. Inner loop = R8.
__global__ __launch_bounds__(256, 4) void attn_kernel(
    const u16* __restrict__ Qbf, const u16* __restrict__ Kbf,
    const u16* __restrict__ Vt, u16* __restrict__ Po16, float* __restrict__ Pl)
{
    __shared__ __align__(16) u16 Pbuf[4][16 * 64];

    const int tid   = threadIdx.x;
    const int w     = tid >> 6;
    const int lane  = tid & 63;
    const int nl    = lane & 15;
    const int quad  = lane >> 4;
    const int b     = blockIdx.x & 3;
    const int g     = (blockIdx.x >> 2) * 4 + w;     // 0..2111, long strips first
    int strip, sp, SP;
    if (g < 1024)      { SP = 16; strip = 192 + (g >> 4); sp = g & 15; }
    else if (g < 1792) { SP = 8; const int h = g - 1024; strip = 96 + (h >> 3); sp = h & 7; }
    else if (g < 2048) { SP = 4; const int h = g - 1792; strip = 32 + (h >> 2); sp = h & 3; }
    else               { SP = 2; const int h = g - 2048; strip = h >> 1;        sp = h & 1; }
    const int wq0 = strip * 16;

    const u16* Kb = Kbf + (size_t)b * T_SEQ * D_HEAD;
    const u16* Vb = Vt  + (size_t)b * D_HEAD * T_SEQ;

    // Q A-frags: A[m=nl][k=quad*8+j], rows wq0+nl
    const u16* qp = Qbf + ((size_t)b * T_SEQ + wq0 + nl) * D_HEAD + quad * 8;
    const bf16x8 qf0 = __builtin_bit_cast(bf16x8, *(const uint4*)qp);
    const bf16x8 qf1 = __builtin_bit_cast(bf16x8, *(const uint4*)(qp + 32));

    f32x4 Ot[4] = {};
    float l[4] = {0.f, 0.f, 0.f, 0.f};
    const int nt = (wq0 + 79) >> 6;              // ceil((wq0+16)/64)
    u16* pb = Pbuf[w];

    for (int kt = sp; kt < nt; kt += SP) {
        const int k0 = kt << 6;

        // K B-frags direct from global (contiguous row bytes)
        uint4 kfr[4][2];
#pragma unroll
        for (int t = 0; t < 4; ++t) {
            const u16* kp = Kb + (size_t)(k0 + t * 16 + nl) * D_HEAD + quad * 8;
            kfr[t][0] = *(const uint4*)kp;
            kfr[t][1] = *(const uint4*)(kp + 32);
        }
        // V B-frags direct from global Vt rows — issued now, consumed after softmax
        uint4 vfr[4][2];
#pragma unroll
        for (int t = 0; t < 4; ++t) {
            const u16* vp = Vb + (size_t)(t * 16 + nl) * T_SEQ + k0 + quad * 8;
            vfr[t][0] = *(const uint4*)vp;
            vfr[t][1] = *(const uint4*)(vp + 32);
        }

        // S = Q K^T
        f32x4 S[4];
#pragma unroll
        for (int t = 0; t < 4; ++t) {
            f32x4 z = {};
            z = __builtin_amdgcn_mfma_f32_16x16x32_bf16(qf0,
                    __builtin_bit_cast(bf16x8, kfr[t][0]), z, 0, 0, 0);
            S[t] = __builtin_amdgcn_mfma_f32_16x16x32_bf16(qf1,
                    __builtin_bit_cast(bf16x8, kfr[t][1]), z, 0, 0, 0);
        }

        // causal mask (fires only on the diagonal tile)
        if (k0 + 63 > wq0) {
#pragma unroll
            for (int t = 0; t < 4; ++t)
#pragma unroll
                for (int reg = 0; reg < 4; ++reg)
                    if (k0 + t * 16 + nl > wq0 + quad * 4 + reg) S[t][reg] = -INFINITY;
        }

        // shift-free softmax: p = exp2(S), per-lane partial row sums
#pragma unroll
        for (int t = 0; t < 4; ++t)
#pragma unroll
            for (int reg = 0; reg < 4; ++reg)
                S[t][reg] = exp2f(S[t][reg]);
#pragma unroll
        for (int reg = 0; reg < 4; ++reg)
            l[reg] += (S[0][reg] + S[1][reg]) + (S[2][reg] + S[3][reg]);

        // P: C-layout -> per-wave LDS -> A-layout (wave-coherent, no barrier)
#pragma unroll
        for (int t = 0; t < 4; ++t) {
            const int gg = 2 * t + (nl >> 3);
#pragma unroll
            for (int reg = 0; reg < 4; ++reg) {
                const int q = quad * 4 + reg;
                pb[q * 64 + ((gg ^ (q & 7)) * 8) + (nl & 7)] = bf16r(S[t][reg]);
            }
        }
        const bf16x8 pf0 = __builtin_bit_cast(bf16x8,
            *(const uint4*)&pb[nl * 64 + ((quad ^ (nl & 7)) * 8)]);
        const bf16x8 pf1 = __builtin_bit_cast(bf16x8,
            *(const uint4*)&pb[nl * 64 + (((4 + quad) ^ (nl & 7)) * 8)]);

        // O += P V
#pragma unroll
        for (int t = 0; t < 4; ++t) {
            Ot[t] = __builtin_amdgcn_mfma_f32_16x16x32_bf16(pf0,
                        __builtin_bit_cast(bf16x8, vfr[t][0]), Ot[t], 0, 0, 0);
            Ot[t] = __builtin_amdgcn_mfma_f32_16x16x32_bf16(pf1,
                        __builtin_bit_cast(bf16x8, vfr[t][1]), Ot[t], 0, 0, 0);
        }
    }

    // reduce l across the 16 col-lanes
#pragma unroll
    for (int reg = 0; reg < 4; ++reg) {
        float s = l[reg];
        s += __shfl_xor(s, 1);
        s += __shfl_xor(s, 2);
        s += __shfl_xor(s, 4);
        s += __shfl_xor(s, 8);
        l[reg] = s;
    }
    // partial O bf16, slot = (b, g): layout [col 64][row 16], reg-pairs contiguous
    u16* po = Po16 + ((size_t)b * NITEMS + g) * 1024;
#pragma unroll
    for (int t = 0; t < 4; ++t) {
        uint2 p2;
        p2.x = pk_bf16(Ot[t][0], Ot[t][1]);
        p2.y = pk_bf16(Ot[t][2], Ot[t][3]);
        *(uint2*)&po[(t * 16 + nl) * 16 + quad * 4] = p2;
    }
    if (nl == 0) {
#pragma unroll
        for (int reg = 0; reg < 4; ++reg)
            Pl[((size_t)b * NITEMS + g) * 16 + quad * 4 + reg] = l[reg];
    }
}

// ---------------- merge variable-split partials: O = (sum Po) / (sum Pl) ----------------
// 1024 blocks (one per b,strip) x 64 thr (thread = col).
__global__ __launch_bounds__(64) void reduce_kernel(
    const u16* __restrict__ Po16, const float* __restrict__ Pl,
    float* __restrict__ O)
{
    __shared__ float linv[16];
    const int bs    = blockIdx.x;
    const int b     = bs >> 8, strip = bs & 255;
    const size_t gr = (size_t)b * T_SEQ + strip * 16;
    const int c     = threadIdx.x;               // col 0..63

    int g0, cnt;
    if (strip >= 192)      { g0 = (strip - 192) * 16;       cnt = 16; }
    else if (strip >= 96)  { g0 = 1024 + (strip - 96) * 8;  cnt = 8; }
    else if (strip >= 32)  { g0 = 1792 + (strip - 32) * 4;  cnt = 4; }
    else                   { g0 = 2048 + strip * 2;         cnt = 2; }
    const size_t base = (size_t)b * NITEMS + g0;

    if (c < 16) {
        float s = 0.f;
        for (int j = 0; j < cnt; ++j) s += Pl[(base + j) * 16 + c];
        linv[c] = 1.0f / s;
    }
    __syncthreads();

    float v[16] = {};
    for (int j = 0; j < cnt; ++j) {
        const u16* p = Po16 + (base + j) * 1024 + c * 16;
        const uint4 x0 = *(const uint4*)p;
        const uint4 x1 = *(const uint4*)(p + 8);
        const unsigned uu[8] = {x0.x, x0.y, x0.z, x0.w, x1.x, x1.y, x1.z, x1.w};
#pragma unroll
        for (int i = 0; i < 8; ++i) {
            v[2*i]   += __builtin_bit_cast(float, uu[i] << 16);
            v[2*i+1] += __builtin_bit_cast(float, uu[i] & 0xFFFF0000u);
        }
    }
#pragma unroll
    for (int r = 0; r < 16; ++r)
        O[(gr + r) * D_HEAD + c] = v[r] * linv[r];
}

extern "C" void kernel_launch(void* const* d_in, const int* in_sizes, int n_in,
                              void* d_out, int out_size, void* d_ws, size_t ws_size,
                              hipStream_t stream) {
    const float* x  = (const float*)d_in[0];
    const float* Wq = (const float*)d_in[1];
    const float* Wk = (const float*)d_in[2];
    const float* Wv = (const float*)d_in[3];
    float* out = (float*)d_out;

    const size_t rows = NROWS;                        // 16384
    u16* Qbf = (u16*)d_ws;                            // 2 MB
    u16* Kbf = Qbf + rows * D_HEAD;                   // 2 MB
    u16* Vt  = Kbf + rows * D_HEAD;                   // 2 MB (per-batch transposed [b][h][t])
    unsigned* Wpk = (unsigned*)(Vt + rows * D_HEAD);  // 384 KB
    u16* Po16 = (u16*)(Wpk + 128 * 192 * 4);          // 4*2112*2KB = 16.5 MB
    float* Pl = (float*)(Po16 + (size_t)NB * NITEMS * 1024);  // 4*2112*64B = 528 KB

    hipLaunchKernelGGL(packw_kernel, dim3(96), dim3(256), 0, stream,
                       Wq, Wk, Wv, Wpk);
    hipLaunchKernelGGL(qkv_kernel, dim3(rows / 32), dim3(256), 0, stream,
                       x, Wpk, Qbf, Kbf, Vt);
    hipLaunchKernelGGL(attn_kernel, dim3(NB * (NITEMS / 4)), dim3(256), 0, stream,
                       Qbf, Kbf, Vt, Po16, Pl);
    hipLaunchKernelGGL(reduce_kernel, dim3(NB * 256), dim3(64), 0, stream,
                       Po16, Pl, out);
}

// Round 12
// 199.003 us; speedup vs baseline: 1.5753x; 1.0025x over previous
//
#include <hip/hip_runtime.h>
#include <hip/hip_bf16.h>

#define D_MODEL 1024
#define D_HEAD  64
#define T_SEQ   4096
#define NB      4
#define NROWS   (NB * T_SEQ)      // 16384
#define SPLIT   8

typedef float f32x4 __attribute__((ext_vector_type(4)));
typedef __bf16 bf16x8 __attribute__((ext_vector_type(8)));
typedef unsigned short u16;

__device__ inline unsigned pk_bf16(float a, float b) {
    unsigned ua = __builtin_bit_cast(unsigned, a);
    unsigned ub = __builtin_bit_cast(unsigned, b);
    ua = (ua + 0x7FFFu + ((ua >> 16) & 1u)) >> 16;   // RNE
    ub = (ub + 0x7FFFu + ((ub >> 16) & 1u)) >> 16;
    return ua | (ub << 16);
}
__device__ inline u16 bf16r(float a) {
    unsigned ua = __builtin_bit_cast(unsigned, a);
    return (u16)((ua + 0x7FFFu + ((ua >> 16) & 1u)) >> 16);
}

// ---------------- W pre-pack: Wpk[kb][n][j] = W_sel[(kb*8+j)*64 + col], bf16 ----------------
__global__ __launch_bounds__(256) void packw_kernel(
    const float* __restrict__ Wq, const float* __restrict__ Wk,
    const float* __restrict__ Wv, unsigned* __restrict__ Wpk)
{
    const int id = blockIdx.x * 256 + threadIdx.x;   // 0..24575
    const int kb = id / 192;
    const int n  = id - kb * 192;
    const int sel = n >> 6, col = n & 63;
    const float* W = sel == 0 ? Wq : (sel == 1 ? Wk : Wv);
    float f[8];
#pragma unroll
    for (int j = 0; j < 8; ++j) f[j] = W[(kb * 8 + j) * 64 + col];
    uint4 o;
    o.x = pk_bf16(f[0], f[1]); o.y = pk_bf16(f[2], f[3]);
    o.z = pk_bf16(f[4], f[5]); o.w = pk_bf16(f[6], f[7]);
    *(uint4*)(Wpk + (size_t)id * 4) = o;
}

// ---------------- QKV projection: streaming LDS-staged GEMM, BK=128 dbuf (R11) --------------
__global__ __launch_bounds__(256) void qkv_kernel(
    const float* __restrict__ x, const unsigned* __restrict__ Wpk,
    u16* __restrict__ Qbf, u16* __restrict__ Kbf, u16* __restrict__ Vt)
{
    __shared__ __align__(16) unsigned Xs[2][32 * 68];   // 32 rows x 128 bf16 (stride 136)
    __shared__ __align__(16) u16 Vbuf[64 * 32];         // V^T bounce: [dim 64][tpos 32]

    const int tid  = threadIdx.x;
    const int w    = tid >> 6;
    const int lane = tid & 63;
    const int nl   = lane & 15;
    const int quad = lane >> 4;
    const long row0 = (long)blockIdx.x * 32;

    const int srow = tid >> 5;          // staging: base row 0..7 (+8 per pass)
    const int scol = (tid & 31) * 4;    // staging col 0..124

    f32x4 acc[2][3] = {};

    float4 nx[4];
#pragma unroll
    for (int p = 0; p < 4; ++p)
        nx[p] = *(const float4*)(x + (row0 + p * 8 + srow) * D_MODEL + scol);

    for (int ch = 0; ch < 8; ++ch) {
        const int buf = ch & 1;
#pragma unroll
        for (int p = 0; p < 4; ++p) {
            uint2 pk2;
            pk2.x = pk_bf16(nx[p].x, nx[p].y);
            pk2.y = pk_bf16(nx[p].z, nx[p].w);
            *(uint2*)&Xs[buf][(p * 8 + srow) * 68 + (scol >> 1)] = pk2;
        }
        __syncthreads();
        if (ch < 7) {
#pragma unroll
            for (int p = 0; p < 4; ++p)
                nx[p] = *(const float4*)(x + (row0 + p * 8 + srow) * D_MODEL
                                           + (ch + 1) * 128 + scol);
        }
#pragma unroll
        for (int kk = 0; kk < 4; ++kk) {
            const bf16x8 a0 = __builtin_bit_cast(bf16x8,
                *(const uint4*)&Xs[buf][nl * 68 + kk * 16 + quad * 4]);
            const bf16x8 a1 = __builtin_bit_cast(bf16x8,
                *(const uint4*)&Xs[buf][(16 + nl) * 68 + kk * 16 + quad * 4]);
            const unsigned* wb = Wpk + (size_t)(ch * 16 + kk * 4 + quad) * 768
                                     + (w * 48 + nl) * 4;
#pragma unroll
            for (int t = 0; t < 3; ++t) {
                const bf16x8 b = __builtin_bit_cast(bf16x8, *(const uint4*)(wb + t * 64));
                acc[0][t] = __builtin_amdgcn_mfma_f32_16x16x32_bf16(a0, b, acc[0][t], 0, 0, 0);
                acc[1][t] = __builtin_amdgcn_mfma_f32_16x16x32_bf16(a1, b, acc[1][t], 0, 0, 0);
            }
        }
        __syncthreads();
    }

    const float QSCALE = 0.04508422f;    // D^-0.5 * log2(e): exp2-domain prescale
#pragma unroll
    for (int t = 0; t < 3; ++t) {
        const int n0c = w * 48 + t * 16;
        const int sel = n0c >> 6;
        const int col = (n0c & 63) + nl;
#pragma unroll
        for (int m = 0; m < 2; ++m) {
            if (sel == 0) {
#pragma unroll
                for (int reg = 0; reg < 4; ++reg)
                    Qbf[(row0 + m * 16 + quad * 4 + reg) * D_HEAD + col] =
                        bf16r(acc[m][t][reg] * QSCALE);
            } else if (sel == 1) {
#pragma unroll
                for (int reg = 0; reg < 4; ++reg)
                    Kbf[(row0 + m * 16 + quad * 4 + reg) * D_HEAD + col] =
                        bf16r(acc[m][t][reg]);
            } else {
                uint2 p2;
                p2.x = pk_bf16(acc[m][t][0], acc[m][t][1]);
                p2.y = pk_bf16(acc[m][t][2], acc[m][t][3]);
                *(uint2*)&Vbuf[col * 32 + m * 16 + quad * 4] = p2;
            }
        }
    }
    __syncthreads();
    {
        const int dim  = tid >> 2;
        const int tseg = (tid & 3) * 8;
        const long bb   = row0 >> 12;
        const int tpos0 = (int)(row0 & 4095);
        const uint4 v = *(const uint4*)&Vbuf[dim * 32 + tseg];
        *(uint4*)&Vt[((bb * 64 + dim) << 12) + tpos0 + tseg] = v;
    }
}

// ---------------- MFMA flash attention: EXACT R10 kernel, launched as 2 half-grids ----------
// gid = blockIdx.x*2 + base: half 0 covers batches {0,2}, half 1 {1,3}; each half spans all
// strips (balanced). Splitting makes qkv/reduce visible in rocprof top-5 (measurement round).
__global__ __launch_bounds__(256, 4) void attn_kernel(
    const u16* __restrict__ Qbf, const u16* __restrict__ Kbf,
    const u16* __restrict__ Vt, u16* __restrict__ Po16, float* __restrict__ Pl,
    int base)
{
    __shared__ __align__(16) u16 Pbuf[4][16 * 64];

    const int tid   = threadIdx.x;
    const int w     = tid >> 6;
    const int lane  = tid & 63;
    const int nl    = lane & 15;
    const int quad  = lane >> 4;
    const int gid   = blockIdx.x * 2 + base;
    const int b     = gid & 3;
    const int idx   = gid >> 2;                  // 0..511
    const int strip = 255 - (idx >> 1);          // long strips dispatched first
    const int sp    = (idx & 1) * 4 + w;         // global split 0..7
    const int wq0   = strip * 16;

    const u16* Kb = Kbf + (size_t)b * T_SEQ * D_HEAD;
    const u16* Vb = Vt  + (size_t)b * D_HEAD * T_SEQ;

    const u16* qp = Qbf + ((size_t)b * T_SEQ + wq0 + nl) * D_HEAD + quad * 8;
    const bf16x8 qf0 = __builtin_bit_cast(bf16x8, *(const uint4*)qp);
    const bf16x8 qf1 = __builtin_bit_cast(bf16x8, *(const uint4*)(qp + 32));

    f32x4 Ot[4] = {};
    float l[4] = {0.f, 0.f, 0.f, 0.f};
    const int nt = (wq0 + 79) >> 6;              // ceil((wq0+16)/64)
    u16* pb = Pbuf[w];

    for (int kt = sp; kt < nt; kt += SPLIT) {
        const int k0 = kt << 6;

        uint4 kfr[4][2];
#pragma unroll
        for (int t = 0; t < 4; ++t) {
            const u16* kp = Kb + (size_t)(k0 + t * 16 + nl) * D_HEAD + quad * 8;
            kfr[t][0] = *(const uint4*)kp;
            kfr[t][1] = *(const uint4*)(kp + 32);
        }
        uint4 vfr[4][2];
#pragma unroll
        for (int t = 0; t < 4; ++t) {
            const u16* vp = Vb + (size_t)(t * 16 + nl) * T_SEQ + k0 + quad * 8;
            vfr[t][0] = *(const uint4*)vp;
            vfr[t][1] = *(const uint4*)(vp + 32);
        }

        f32x4 S[4];
#pragma unroll
        for (int t = 0; t < 4; ++t) {
            f32x4 z = {};
            z = __builtin_amdgcn_mfma_f32_16x16x32_bf16(qf0,
                    __builtin_bit_cast(bf16x8, kfr[t][0]), z, 0, 0, 0);
            S[t] = __builtin_amdgcn_mfma_f32_16x16x32_bf16(qf1,
                    __builtin_bit_cast(bf16x8, kfr[t][1]), z, 0, 0, 0);
        }

        if (k0 + 63 > wq0) {
#pragma unroll
            for (int t = 0; t < 4; ++t)
#pragma unroll
                for (int reg = 0; reg < 4; ++reg)
                    if (k0 + t * 16 + nl > wq0 + quad * 4 + reg) S[t][reg] = -INFINITY;
        }

#pragma unroll
        for (int t = 0; t < 4; ++t)
#pragma unroll
            for (int reg = 0; reg < 4; ++reg)
                S[t][reg] = exp2f(S[t][reg]);
#pragma unroll
        for (int reg = 0; reg < 4; ++reg)
            l[reg] += (S[0][reg] + S[1][reg]) + (S[2][reg] + S[3][reg]);

#pragma unroll
        for (int t = 0; t < 4; ++t) {
            const int g = 2 * t + (nl >> 3);
#pragma unroll
            for (int reg = 0; reg < 4; ++reg) {
                const int q = quad * 4 + reg;
                pb[q * 64 + ((g ^ (q & 7)) * 8) + (nl & 7)] = bf16r(S[t][reg]);
            }
        }
        const bf16x8 pf0 = __builtin_bit_cast(bf16x8,
            *(const uint4*)&pb[nl * 64 + ((quad ^ (nl & 7)) * 8)]);
        const bf16x8 pf1 = __builtin_bit_cast(bf16x8,
            *(const uint4*)&pb[nl * 64 + (((4 + quad) ^ (nl & 7)) * 8)]);

#pragma unroll
        for (int t = 0; t < 4; ++t) {
            Ot[t] = __builtin_amdgcn_mfma_f32_16x16x32_bf16(pf0,
                        __builtin_bit_cast(bf16x8, vfr[t][0]), Ot[t], 0, 0, 0);
            Ot[t] = __builtin_amdgcn_mfma_f32_16x16x32_bf16(pf1,
                        __builtin_bit_cast(bf16x8, vfr[t][1]), Ot[t], 0, 0, 0);
        }
    }

#pragma unroll
    for (int reg = 0; reg < 4; ++reg) {
        float s = l[reg];
        s += __shfl_xor(s, 1);
        s += __shfl_xor(s, 2);
        s += __shfl_xor(s, 4);
        s += __shfl_xor(s, 8);
        l[reg] = s;
    }
    const int bs = b * 256 + strip;
    u16* po = Po16 + ((size_t)sp * 1024 + bs) * 1024;
#pragma unroll
    for (int t = 0; t < 4; ++t) {
        uint2 p2;
        p2.x = pk_bf16(Ot[t][0], Ot[t][1]);
        p2.y = pk_bf16(Ot[t][2], Ot[t][3]);
        *(uint2*)&po[(t * 16 + nl) * 16 + quad * 4] = p2;
    }
    if (nl == 0) {
        const size_t gr = (size_t)b * T_SEQ + wq0;
#pragma unroll
        for (int reg = 0; reg < 4; ++reg)
            Pl[(size_t)sp * NROWS + gr + quad * 4 + reg] = l[reg];
    }
}

// ---------------- merge K-split partials: O[row][col] = sum_sp Po / sum_sp Pl (R10) ---------
__global__ __launch_bounds__(64) void reduce_kernel(
    const u16* __restrict__ Po16, const float* __restrict__ Pl,
    float* __restrict__ O)
{
    __shared__ float linv[16];
    const int bs    = blockIdx.x;
    const int b     = bs >> 8, strip = bs & 255;
    const size_t gr = (size_t)b * T_SEQ + strip * 16;
    const int c     = threadIdx.x;               // col 0..63

    if (c < 16) {
        float s = 0.f;
#pragma unroll
        for (int sp = 0; sp < SPLIT; ++sp) s += Pl[(size_t)sp * NROWS + gr + c];
        linv[c] = 1.0f / s;
    }
    __syncthreads();

    float v[16] = {};
#pragma unroll
    for (int sp = 0; sp < SPLIT; ++sp) {
        const u16* p = Po16 + ((size_t)sp * 1024 + bs) * 1024 + c * 16;
        const uint4 x0 = *(const uint4*)p;
        const uint4 x1 = *(const uint4*)(p + 8);
        const unsigned uu[8] = {x0.x, x0.y, x0.z, x0.w, x1.x, x1.y, x1.z, x1.w};
#pragma unroll
        for (int i = 0; i < 8; ++i) {
            v[2*i]   += __builtin_bit_cast(float, uu[i] << 16);
            v[2*i+1] += __builtin_bit_cast(float, uu[i] & 0xFFFF0000u);
        }
    }
#pragma unroll
    for (int r = 0; r < 16; ++r)
        O[(gr + r) * D_HEAD + c] = v[r] * linv[r];
}

extern "C" void kernel_launch(void* const* d_in, const int* in_sizes, int n_in,
                              void* d_out, int out_size, void* d_ws, size_t ws_size,
                              hipStream_t stream) {
    const float* x  = (const float*)d_in[0];
    const float* Wq = (const float*)d_in[1];
    const float* Wk = (const float*)d_in[2];
    const float* Wv = (const float*)d_in[3];
    float* out = (float*)d_out;

    const size_t rows = NROWS;                        // 16384
    u16* Qbf = (u16*)d_ws;                            // 2 MB
    u16* Kbf = Qbf + rows * D_HEAD;                   // 2 MB
    u16* Vt  = Kbf + rows * D_HEAD;                   // 2 MB (per-batch transposed [b][h][t])
    unsigned* Wpk = (unsigned*)(Vt + rows * D_HEAD);  // 384 KB
    u16* Po16 = (u16*)(Wpk + 128 * 192 * 4);          // SPLIT*16384*64 bf16 = 16 MB
    float* Pl = (float*)(Po16 + (size_t)SPLIT * rows * D_HEAD);  // 512 KB

    hipLaunchKernelGGL(packw_kernel, dim3(96), dim3(256), 0, stream,
                       Wq, Wk, Wv, Wpk);
    hipLaunchKernelGGL(qkv_kernel, dim3(rows / 32), dim3(256), 0, stream,
                       x, Wpk, Qbf, Kbf, Vt);
    hipLaunchKernelGGL(attn_kernel, dim3(NB * 256), dim3(256), 0, stream,
                       Qbf, Kbf, Vt, Po16, Pl, 0);
    hipLaunchKernelGGL(attn_kernel, dim3(NB * 256), dim3(256), 0, stream,
                       Qbf, Kbf, Vt, Po16, Pl, 1);
    hipLaunchKernelGGL(reduce_kernel, dim3(NB * 256), dim3(64), 0, stream,
                       Po16, Pl, out);
}